// Round 5
// baseline (136.143 us; speedup 1.0000x reference)
//
#include <hip/hip_runtime.h>
#include <cmath>

#define P 5
#define LBV 0.0f
#define UBV 0.5f
#define RFV 1.03f
#define ALPHA 0.1f
#define OMEGA 0.05f
#define BETA 0.05f
#define MU 0.01f
#define NTHR 256

#define AS1 __attribute__((address_space(1)))
#define AS3 __attribute__((address_space(3)))

// tanh via HW v_exp_f32 + v_rcp_f32. For |x| large, exp(-2|x|)->0 => r->1.
__device__ __forceinline__ float fast_tanh(float x) {
    float ax = fabsf(x);
    float t  = __expf(-2.0f * ax);
    float r  = (1.0f - t) * __builtin_amdgcn_rcpf(1.0f + t);
    return copysignf(r, x);
}

// One thread per sample. Only layer k=3 contributes to the output (reference
// loop re-consumes the ORIGINAL x1/x2; only the last iteration survives).
//
// R4 lesson: the two block-wide barriers couple 4 waves (all wait for the
// slowest DMA / slowest rebalance). This version is BARRIER-FREE: each wave
// stages its own 64 samples into a private LDS region, waits on its own
// vmcnt, computes, rewrites its region with cov, and stores it out. Waves on
// a CU pipeline independently (20 resident waves at mixed stages).
__global__ __launch_bounds__(NTHR, 5) void portfolio_kernel(
    const float* __restrict__ x1,
    const float* __restrict__ x2,
    const float* __restrict__ eps,
    const float* __restrict__ W,
    float* __restrict__ out, int B)
{
    __shared__ alignas(16) float sX2[4 * 1600];   // 25.6 KB, 1600 floats/wave
    __shared__ alignas(16) float sE[4 * 320];     // 5.12 KB, 320 floats/wave

    const int tid  = threadIdx.x;
    const int lane = tid & 63;
    const int wv   = tid >> 6;                    // wave id, uniform
    const int bw   = blockIdx.x * NTHR + wv * 64; // this wave's first sample

    float x1v = x1[bw + lane];                    // coalesced direct load

    // ---- per-wave DMA staging (wave-uniform LDS base + lane*size) ----
    const float* gx2  = x2 + (size_t)bw * (P * P);        // 1600 floats
    float*       ldsx = &sX2[wv * 1600];
    #pragma unroll
    for (int i = 0; i < 6; ++i)
        __builtin_amdgcn_global_load_lds((const AS1 void*)(gx2 + i * 256 + lane * 4),
                                         (AS3 void*)(ldsx + i * 256), 16, 0, 0);
    __builtin_amdgcn_global_load_lds((const AS1 void*)(gx2 + 1536 + lane),
                                     (AS3 void*)(ldsx + 1536), 4, 0, 0);

    const float* ge   = eps + (size_t)3 * B * P + (size_t)bw * P;  // 320 floats
    float*       ldse = &sE[wv * 320];
    __builtin_amdgcn_global_load_lds((const AS1 void*)(ge + lane * 4),
                                     (AS3 void*)(ldse), 16, 0, 0);
    __builtin_amdgcn_global_load_lds((const AS1 void*)(ge + 256 + lane),
                                     (AS3 void*)(ldse + 256), 4, 0, 0);

    // Wave-local drain of this wave's DMAs (no s_barrier!). vmcnt(0),
    // lgkmcnt/expcnt = no-wait; sched_barrier pins ds_reads below it.
    __builtin_amdgcn_sched_barrier(0);
    __builtin_amdgcn_s_waitcnt(0x0F70);
    __builtin_amdgcn_sched_barrier(0);

    // Own x2 row (lane stride 25 words -> 2 lanes/bank, free).
    float r2[P * P];
    #pragma unroll
    for (int i = 0; i < P * P; ++i) r2[i] = ldsx[lane * (P * P) + i];

    float e[P];
    #pragma unroll
    for (int j = 0; j < P; ++j) e[j] = ldse[lane * P + j];

    // Ce[i] = sum_j x2[i][j] * eps[j]
    float Ce[P];
    #pragma unroll
    for (int i = 0; i < P; ++i) {
        float s = 0.0f;
        #pragma unroll
        for (int j = 0; j < P; ++j) s = fmaf(r2[i * P + j], e[j], s);
        Ce[i] = s;
    }

    float R[P], h[P];
    #pragma unroll
    for (int i = 0; i < P; ++i) { R[i] = MU + Ce[i]; h[i] = R[i]; }

    // 3 bias-free Linear(5,5) + tanh. W[3] is wave-uniform -> s_loads.
    const float* Wl = W + 3 * 3 * P * P;
    #pragma unroll
    for (int l = 0; l < 3; ++l) {
        float hn[P];
        #pragma unroll
        for (int i = 0; i < P; ++i) {
            float s = 0.0f;
            #pragma unroll
            for (int j = 0; j < P; ++j) s = fmaf(h[j], Wl[l * P * P + i * P + j], s);
            hn[i] = fast_tanh(s);
        }
        #pragma unroll
        for (int i = 0; i < P; ++i) h[i] = hn[i];
    }

    // softmax over P — h in (-1,1) so no max-subtraction needed
    float w[P], ssum = 0.0f;
    #pragma unroll
    for (int i = 0; i < P; ++i) { w[i] = __expf(h[i]); ssum += w[i]; }
    float rs = __builtin_amdgcn_rcpf(ssum);
    #pragma unroll
    for (int i = 0; i < P; ++i) w[i] *= rs;

    // water-filling rebalance; break==freeze (matches reference semantics)
    float oldv[P], nw[P];
    #pragma unroll
    for (int i = 0; i < P; ++i) {
        oldv[i] = w[i];
        nw[i]   = fminf(fmaxf(w[i], LBV), UBV);
    }
    #pragma unroll
    for (int it = 0; it < 8; ++it) {
        float leftover = 0.0f;
        #pragma unroll
        for (int i = 0; i < P; ++i) leftover += oldv[i] - nw[i];
        float mk[P], msum = 0.0f;
        #pragma unroll
        for (int i = 0; i < P; ++i) {
            mk[i] = (nw[i] != UBV) ? nw[i] : 0.0f;
            msum += mk[i];
        }
        float scale = leftover * __builtin_amdgcn_rcpf(msum);
        float n2[P];
        #pragma unroll
        for (int i = 0; i < P; ++i) n2[i] = fmaf(scale, mk[i], nw[i]);
        bool cont = false;
        #pragma unroll
        for (int i = 0; i < P; ++i) cont = cont || (n2[i] > UBV);
        #pragma unroll
        for (int i = 0; i < P; ++i) {
            oldv[i] = n2[i];
            nw[i]   = cont ? fminf(fmaxf(n2[i], LBV), UBV) : n2[i];
        }
        if (!cont) break;
    }

    // wealth = x1 * RF * sum_i nw[i] * (1 + R[i])  (coalesced store)
    float ws = 0.0f;
    #pragma unroll
    for (int i = 0; i < P; ++i) ws = fmaf(nw[i], 1.0f + R[i], ws);
    out[bw + lane] = x1v * ws * RFV;

    // cov back into own LDS slot (same-wave only -> DS pipe order suffices)
    float ce2[P];
    #pragma unroll
    for (int j = 0; j < P; ++j) ce2[j] = Ce[j] * Ce[j];
    #pragma unroll
    for (int i = 0; i < P; ++i) {
        #pragma unroll
        for (int j = 0; j < P; ++j)
            ldsx[lane * (P * P) + i * P + j] =
                fmaf(BETA, ce2[j], fmaf(ALPHA, r2[i * P + j], OMEGA));
    }

    // coalesced store-out of this wave's 1600-float region: 6 float4 + 1 dword
    float* gout = out + B + (size_t)bw * (P * P);
    const float4* s4 = (const float4*)ldsx;
    float4* g4 = (float4*)gout;
    #pragma unroll
    for (int r = 0; r < 6; ++r)
        g4[r * 64 + lane] = s4[r * 64 + lane];
    gout[1536 + lane] = ldsx[1536 + lane];
}

extern "C" void kernel_launch(void* const* d_in, const int* in_sizes, int n_in,
                              void* d_out, int out_size, void* d_ws, size_t ws_size,
                              hipStream_t stream) {
    const float* x1  = (const float*)d_in[0];
    const float* x2  = (const float*)d_in[1];
    const float* eps = (const float*)d_in[2];
    const float* W   = (const float*)d_in[3];
    float* out = (float*)d_out;
    const int B = in_sizes[0];           // 524288
    const int blocks = B / NTHR;
    portfolio_kernel<<<blocks, NTHR, 0, stream>>>(x1, x2, eps, W, out, B);
}